// Round 1
// baseline (416.046 us; speedup 1.0000x reference)
//
#include <hip/hip_runtime.h>
#include <hip/hip_fp16.h>

// ---------------------------------------------------------------------------
// FormulaNet GCN forward: 3x GCNConv(128) + mean-pool(512 graphs) + dense.
// R2: fp16 node tensors. R4: bucket-sort CSR. R7: prep mega-kernel.
// R10/R12/R15/R16: paired gathers, aggsum LDS slots, occupancy. [BEST 356.8]
// R17: XCD column-split agg. FETCH for agg = 8 XCD x touched footprint
//      (compulsory per-XCD; cross-XCD reuse never captured). Split feature
//      dim by XCD group (bid%8>>2 -> cols 0..63 / 64..127) so per-XCD
//      footprint halves: predicted FETCH 201->~110 MB per agg pass.
//      Cost: mm unfused from agg (new k_mm, MFMA, ~13us) since mm needs all
//      128 K-dims. k_mm pre-scales output rows by dis[node], so layers 2/3
//      drop per-edge dis loads (plain adds, shorter dep chain).
// ---------------------------------------------------------------------------

#define BSHIFT 8
#define BSZ    256          // nodes per bucket
#define MAXBKT 512          // LDS sizing bound (N <= 131072)
#define CPAD   32           // 1 counter / 128 B line for global cursors
#define CAPSH  13           // 8192 staged/col slots per bucket

typedef _Float16 half8 __attribute__((ext_vector_type(8)));
typedef float f32x4 __attribute__((ext_vector_type(4)));

#define RFL __builtin_amdgcn_readfirstlane

// ---- prep: bin | layer1 | cvtW | bounds | zero(sums), by block range ----
__global__ __launch_bounds__(512) void k_prep(
        const float* __restrict__ x, const float* __restrict__ Wd1,
        const float* __restrict__ bd1, const float* __restrict__ Wg1,
        __half* __restrict__ g,
        const float* __restrict__ W2, const float* __restrict__ W3,
        __half* __restrict__ WT2, __half* __restrict__ WT3,
        const int* __restrict__ batch, int* __restrict__ gs,
        const int* __restrict__ src, const int* __restrict__ dst,
        int* __restrict__ bktFill, int* __restrict__ staged,
        float* __restrict__ sums,
        int N, int NG, int E, int nbkt, int BINB, int L1B, int NB1) {
    __shared__ float sW[512];
    __shared__ int hh[MAXBKT], base[MAXBKT], cur[MAXBKT];
    int bid = blockIdx.x;
    int t = threadIdx.x;
    if (bid < BINB) {
        // ---- bin: 4096 edges/block; LDS hist -> reservation -> scatter
        for (int i = t; i < nbkt; i += 512) { hh[i] = 0; cur[i] = 0; }
        __syncthreads();
        int e0 = bid * 4096 + t;
#pragma unroll
        for (int k = 0; k < 8; k++) {
            int e = e0 + k * 512;
            if (e < E) atomicAdd(&hh[dst[e] >> BSHIFT], 1);
        }
        __syncthreads();
        for (int i = t; i < nbkt; i += 512)
            base[i] = hh[i] ? atomicAdd(&bktFill[(size_t)i * CPAD], hh[i]) : 0;
        __syncthreads();
#pragma unroll
        for (int k = 0; k < 8; k++) {
            int e = e0 + k * 512;
            if (e < E) {
                int d = dst[e], s = src[e];
                int b = d >> BSHIFT;
                int off = atomicAdd(&cur[b], 1);
                staged[((size_t)b << CAPSH) + base[b] + off] =
                    ((d & (BSZ - 1)) << 17) | s;
            }
        }
    } else if (bid < BINB + L1B) {
        // ---- layer1: 64 nodes/block; h0 = relu(x@Wd1+bd1); g = h0@Wg1
        int rb = bid - BINB;
        sW[t] = Wg1[t];
        __syncthreads();
        int j = t & 127;
#pragma unroll 4
        for (int it = 0; it < 16; ++it) {
            int node = rb * 64 + it * 4 + (t >> 7);
            if (node < N) {
                float4 xv = ((const float4*)x)[node];
                float acc = 0.f;
#pragma unroll
                for (int k = 0; k < 4; k++) {
                    float h0 = xv.x * Wd1[k] + xv.y * Wd1[4 + k]
                             + xv.z * Wd1[8 + k] + xv.w * Wd1[12 + k] + bd1[k];
                    h0 = fmaxf(h0, 0.f);
                    acc = fmaf(h0, sW[k * 128 + j], acc);
                }
                g[(size_t)node * 128 + j] = __float2half_rn(acc);
            }
        }
    } else if (bid < BINB + L1B + 32) {
        // ---- cvtW: W fp32 [k][n] -> WT fp16 [n][k], both layers
        int t2 = (bid - BINB - L1B) * 512 + t;      // 0..16383
        int k = t2 >> 7, nn = t2 & 127;
        WT2[nn * 128 + k] = __float2half_rn(W2[t2]);
        WT3[nn * 128 + k] = __float2half_rn(W3[t2]);
    } else if (bid < BINB + L1B + 32 + NB1) {
        // ---- bounds: batch sorted -> per-graph node ranges
        int i = (bid - BINB - L1B - 32) * 512 + t;
        if (i >= N) return;
        int b = batch[i];
        int prev = (i == 0) ? -1 : batch[i - 1];
        for (int g2 = prev + 1; g2 <= b; ++g2) gs[g2] = i;
        if (i == N - 1)
            for (int g2 = b + 1; g2 <= NG; ++g2) gs[g2] = N;
    } else {
        // ---- zero sums
        int idx = (bid - BINB - L1B - 32 - NB1) * 512 + t;
        if (idx < NG * 128) sums[idx] = 0.f;
    }
}

// ---- per-bucket: fused load+hist into LDS cache -> scan -> LDS scatter ----
__global__ __launch_bounds__(1024) void k_fineB(
        const int* __restrict__ staged, const int* __restrict__ bktFill,
        int2* __restrict__ rpe, float* __restrict__ dis,
        int* __restrict__ col, int N) {
    __shared__ int sEnt[1 << CAPSH];        // 32 KB bucket cache
    __shared__ int cnt[BSZ];
    __shared__ int incl[BSZ];
    int b = blockIdx.x;
    int lo = b << CAPSH;
    int cntE = bktFill[(size_t)b * CPAD];
    int n0 = b << BSHIFT;
    int tid = threadIdx.x;
    if (tid < BSZ) cnt[tid] = 0;
    __syncthreads();
    // fused: stage entries in LDS + histogram
    for (int e = tid; e < cntE; e += 1024) {
        int v = staged[lo + e];
        sEnt[e] = v;
        atomicAdd(&cnt[v >> 17], 1);
    }
    __syncthreads();
    int v = 0;
    if (tid < BSZ) { v = cnt[tid]; incl[tid] = v; }
    for (int off = 1; off < BSZ; off <<= 1) {
        __syncthreads();
        int t = (tid < BSZ && tid >= off) ? incl[tid - off] : 0;
        __syncthreads();
        if (tid < BSZ) incl[tid] += t;
    }
    __syncthreads();
    int myofs = 0;
    if (tid < BSZ) {
        myofs = incl[tid] - v;                 // exclusive
        int node = n0 + tid;
        if (node < N) {
            rpe[node] = make_int2(lo + myofs, lo + myofs + v);
            dis[node] = rsqrtf((float)(v + 1));    // +1: self-loop
        }
    }
    __syncthreads();
    // reuse incl[] as base table, cnt[] as cursors
    if (tid < BSZ) { incl[tid] = myofs; cnt[tid] = 0; }
    __syncthreads();
    for (int e = tid; e < cntE; e += 1024) {
        int ent = sEnt[e];
        int dl = ent >> 17;
        int pos = lo + incl[dl] + atomicAdd(&cnt[dl], 1);
        col[pos] = ent & 0x1FFFF;
    }
}

// ---- half-row (64-feat) aggregation: quarter-wave qw covers every-4th
// edge; 16 lanes x 8 B = 128 B per edge-half. xor16/xor32 combines quarters.
__device__ __forceinline__ void acc4h(float acc[4], uint2 v, float w) {
    float2 a01 = __half22float2(*(__half2*)&v.x);
    float2 a23 = __half22float2(*(__half2*)&v.y);
    acc[0] = fmaf(w, a01.x, acc[0]);
    acc[1] = fmaf(w, a01.y, acc[1]);
    acc[2] = fmaf(w, a23.x, acc[2]);
    acc[3] = fmaf(w, a23.y, acc[3]);
}

template<bool DIS>          // DIS: load per-edge dis[src] (layer1, unscaled in)
__device__ __forceinline__ void agg_half(
        const __half* __restrict__ gin, const int* __restrict__ col,
        const float* __restrict__ dis, int r0, int r1, int node,
        float di, int qw, int cs, float acc[4]) {
    uint2 mr = *(const uint2*)(gin + (size_t)node * 128 + cs);
    float2 m01 = __half22float2(*(__half2*)&mr.x);
    float2 m23 = __half22float2(*(__half2*)&mr.y);
    float sw = (qw == 0) ? (DIS ? di : 1.f) : 0.f;   // self-loop once
    acc[0] = sw * m01.x; acc[1] = sw * m01.y;
    acc[2] = sw * m23.x; acc[3] = sw * m23.y;
    int e = r0 + qw;
    for (; e + 12 < r1; e += 16) {                   // 4 rows in flight/lane
        int c0 = col[e], c1 = col[e + 4], c2 = col[e + 8], c3 = col[e + 12];
        float w0 = DIS ? dis[c0] : 1.f;
        float w1 = DIS ? dis[c1] : 1.f;
        float w2 = DIS ? dis[c2] : 1.f;
        float w3 = DIS ? dis[c3] : 1.f;
        uint2 v0 = *(const uint2*)(gin + (size_t)c0 * 128 + cs);
        uint2 v1 = *(const uint2*)(gin + (size_t)c1 * 128 + cs);
        uint2 v2 = *(const uint2*)(gin + (size_t)c2 * 128 + cs);
        uint2 v3 = *(const uint2*)(gin + (size_t)c3 * 128 + cs);
        acc4h(acc, v0, w0); acc4h(acc, v1, w1);
        acc4h(acc, v2, w2); acc4h(acc, v3, w3);
    }
    for (; e + 4 < r1; e += 8) {
        int c0 = col[e], c1 = col[e + 4];
        float w0 = DIS ? dis[c0] : 1.f;
        float w1 = DIS ? dis[c1] : 1.f;
        uint2 v0 = *(const uint2*)(gin + (size_t)c0 * 128 + cs);
        uint2 v1 = *(const uint2*)(gin + (size_t)c1 * 128 + cs);
        acc4h(acc, v0, w0); acc4h(acc, v1, w1);
    }
    if (e < r1) {
        int c0 = col[e];
        float w0 = DIS ? dis[c0] : 1.f;
        uint2 v0 = *(const uint2*)(gin + (size_t)c0 * 128 + cs);
        acc4h(acc, v0, w0);
    }
#pragma unroll
    for (int k = 0; k < 4; k++) {
        acc[k] += __shfl_xor(acc[k], 16);
        acc[k] += __shfl_xor(acc[k], 32);
    }
}

// XCD column-split agg: bid%8 -> XCD (empirical round-robin). XCDs 0-3 own
// feats 0..63, XCDs 4-7 own 64..127, so per-XCD touched footprint of gin is
// 12.8 MB not 25.6. nb=(bid>>3)*4+(bid&3), h=(bid>>2)&1 is a bijection over
// (node-block, half). Block = 16 nodes x 4 waves, 4 serial nodes/wave.
// Output: xout[node][h*64..] = relu(di*acc + b) fp16 (layer output x_l).
template<bool DIS>
__global__ __launch_bounds__(256) void k_aggH(
        const __half* __restrict__ gin, const int2* __restrict__ rpe,
        const int* __restrict__ col, const float* __restrict__ dis,
        const float* __restrict__ bias, __half* __restrict__ xout,
        int n, int nb16) {
    int bid = blockIdx.x;
    int nb = (bid >> 3) * 4 + (bid & 3);
    int h = (bid >> 2) & 1;
    if (nb >= nb16) return;
    int t = threadIdx.x;
    int wave = t >> 6, lane = t & 63;
    int qw = lane >> 4, s16 = lane & 15;
    int cs = (h << 6) + s16 * 4;            // col offset in halves
    float4 bb = ((const float4*)bias)[(h << 4) + s16];
#pragma unroll
    for (int i = 0; i < 4; i++) {
        int node = RFL(nb * 16 + wave * 4 + i);
        if (node < n) {
            int2 re = rpe[node];
            int r0 = RFL(re.x), r1 = RFL(re.y);
            float di = dis[node];
            float acc[4];
            agg_half<DIS>(gin, col, dis, r0, r1, node, di, qw, cs, acc);
            if (qw == 0) {
                __half2 o01 = __floats2half2_rn(
                    fmaxf(fmaf(di, acc[0], bb.x), 0.f),
                    fmaxf(fmaf(di, acc[1], bb.y), 0.f));
                __half2 o23 = __floats2half2_rn(
                    fmaxf(fmaf(di, acc[2], bb.z), 0.f),
                    fmaxf(fmaf(di, acc[3], bb.w), 0.f));
                uint2 pk;
                pk.x = *(unsigned*)&o01; pk.y = *(unsigned*)&o23;
                *(uint2*)(xout + (size_t)node * 128 + cs) = pk;
            }
        }
    }
}

// mm pass: gout[node] = dis[node] * (xin[node] @ W)  (fp16 in/out, MFMA).
// dis pre-scale means the consumer agg adds plain rows (no per-edge dis).
__global__ __launch_bounds__(256) void k_mm(
        const __half* __restrict__ xin, const __half* __restrict__ WT,
        const float* __restrict__ dis, __half* __restrict__ gout, int n) {
    __shared__ _Float16 sH[16 * 136];
    __shared__ _Float16 sO[16 * 136];
    __shared__ float sDis[16];
    int t = threadIdx.x;
    int node0 = blockIdx.x * 16;
    int row = t >> 4, seg = t & 15;
    int nodeR = node0 + row;
    if (nodeR < n)
        *(uint4*)&sH[row * 136 + seg * 8] =
            *(const uint4*)(xin + (size_t)nodeR * 128 + seg * 8);
    else {
        uint4 z = {0, 0, 0, 0};
        *(uint4*)&sH[row * 136 + seg * 8] = z;
    }
    if (t < 16) sDis[t] = (node0 + t < n) ? dis[node0 + t] : 0.f;
    __syncthreads();
    int wave = t >> 6, lane = t & 63;
    int q = lane >> 4, c = lane & 15;
    int n0 = wave * 32;
    f32x4 acc0 = {0.f, 0.f, 0.f, 0.f}, acc1 = {0.f, 0.f, 0.f, 0.f};
#pragma unroll
    for (int ks = 0; ks < 4; ks++) {
        int k0 = ks * 32;
        half8 a  = *(half8*)&sH[c * 136 + k0 + q * 8];
        half8 b0 = *(const half8*)(WT + (size_t)(n0 + c) * 128 + k0 + q * 8);
        half8 b1 = *(const half8*)(WT + (size_t)(n0 + 16 + c) * 128 + k0 + q * 8);
        acc0 = __builtin_amdgcn_mfma_f32_16x16x32_f16(a, b0, acc0, 0, 0, 0);
        acc1 = __builtin_amdgcn_mfma_f32_16x16x32_f16(a, b1, acc1, 0, 0, 0);
    }
#pragma unroll
    for (int r = 0; r < 4; r++) {
        int rr = q * 4 + r;
        sO[rr * 136 + n0 + c]      = (_Float16)(acc0[r] * sDis[rr]);
        sO[rr * 136 + n0 + 16 + c] = (_Float16)(acc1[r] * sDis[rr]);
    }
    __syncthreads();
    if (node0 + row < n)
        *(uint4*)(gout + (size_t)(node0 + row) * 128 + seg * 8) =
            *(uint4*)&sO[row * 136 + seg * 8];
}

// layer-3 agg + mean-pool, column-split like k_aggH (input pre-scaled).
// Single-graph blocks: per-wave register partials -> private LDS slots ->
// one barrier -> 64 global atomics per block (this half's feats).
__global__ __launch_bounds__(256) void k_aggsumH(
        const __half* __restrict__ gin, const int2* __restrict__ rpe,
        const int* __restrict__ col, const float* __restrict__ dis,
        const float* __restrict__ bias, const int* __restrict__ batch,
        float* __restrict__ sums, int n, int nb16) {
    __shared__ float ls[4][64];
    int bid = blockIdx.x;
    int nb = (bid >> 3) * 4 + (bid & 3);
    int h = (bid >> 2) & 1;
    if (nb >= nb16) return;
    int nodeBase = nb * 16;
    if (nodeBase >= n) return;
    int t = threadIdx.x;
    int wave = t >> 6, lane = t & 63;
    int qw = lane >> 4, s16 = lane & 15;
    int cs = (h << 6) + s16 * 4;
    int lastNode = min(nodeBase + 15, n - 1);
    int b0 = RFL(batch[nodeBase]);
    bool uni = (RFL(batch[lastNode]) == b0);
    float4 bb = ((const float4*)bias)[(h << 4) + s16];
    float sx[4] = {0.f, 0.f, 0.f, 0.f};
    int curb = b0;
#pragma unroll
    for (int i = 0; i < 4; i++) {
        int node = RFL(nodeBase + wave * 4 + i);
        if (node < n) {
            int2 re = rpe[node];
            int r0 = RFL(re.x), r1 = RFL(re.y);
            float di = dis[node];
            float acc[4];
            agg_half<false>(gin, col, dis, r0, r1, node, di, qw, cs, acc);
            float o0 = fmaxf(fmaf(di, acc[0], bb.x), 0.f);
            float o1 = fmaxf(fmaf(di, acc[1], bb.y), 0.f);
            float o2 = fmaxf(fmaf(di, acc[2], bb.z), 0.f);
            float o3 = fmaxf(fmaf(di, acc[3], bb.w), 0.f);
            if (!uni) {
                int b = RFL(batch[node]);
                if (b != curb) {
                    if (qw == 0) {
                        atomicAdd(&sums[(size_t)curb * 128 + cs + 0], sx[0]);
                        atomicAdd(&sums[(size_t)curb * 128 + cs + 1], sx[1]);
                        atomicAdd(&sums[(size_t)curb * 128 + cs + 2], sx[2]);
                        atomicAdd(&sums[(size_t)curb * 128 + cs + 3], sx[3]);
                    }
                    sx[0] = sx[1] = sx[2] = sx[3] = 0.f;
                    curb = b;
                }
            }
            sx[0] += o0; sx[1] += o1; sx[2] += o2; sx[3] += o3;
        }
    }
    if (uni) {
        if (qw == 0) {
            ls[wave][s16 * 4 + 0] = sx[0];
            ls[wave][s16 * 4 + 1] = sx[1];
            ls[wave][s16 * 4 + 2] = sx[2];
            ls[wave][s16 * 4 + 3] = sx[3];
        }
        __syncthreads();
        if (t < 64) {
            float v = ls[0][t] + ls[1][t] + ls[2][t] + ls[3][t];
            atomicAdd(&sums[(size_t)b0 * 128 + (h << 6) + t], v);
        }
    } else {
        if (qw == 0) {
            atomicAdd(&sums[(size_t)curb * 128 + cs + 0], sx[0]);
            atomicAdd(&sums[(size_t)curb * 128 + cs + 1], sx[1]);
            atomicAdd(&sums[(size_t)curb * 128 + cs + 2], sx[2]);
            atomicAdd(&sums[(size_t)curb * 128 + cs + 3], sx[3]);
        }
    }
}

// head: pooled = sums/cnt; out = pooled @ Wd2 + bd2. One block per graph.
__global__ __launch_bounds__(128) void k_head(
        const float* __restrict__ sums, const int* __restrict__ gs,
        const float* __restrict__ Wd2, const float* __restrict__ bd2,
        float* __restrict__ out) {
    int gidx = blockIdx.x;
    int j = threadIdx.x;
    int c = gs[gidx + 1] - gs[gidx];
    float inv = 1.0f / (float)(c > 1 ? c : 1);
    __shared__ float sp[128];
    sp[j] = sums[(size_t)gidx * 128 + j] * inv;
    __syncthreads();
    float o = bd2[j];
#pragma unroll 8
    for (int k = 0; k < 128; k++) o = fmaf(sp[k], Wd2[k * 128 + j], o);
    out[gidx * 128 + j] = o;
}

extern "C" void kernel_launch(void* const* d_in, const int* in_sizes, int n_in,
                              void* d_out, int out_size, void* d_ws, size_t ws_size,
                              hipStream_t stream) {
    const float* x   = (const float*)d_in[0];
    const int*  ei   = (const int*)d_in[1];
    const int* batch = (const int*)d_in[2];
    const float* Wd1 = (const float*)d_in[3];
    const float* bd1 = (const float*)d_in[4];
    const float* Wg1 = (const float*)d_in[5];
    const float* bg1 = (const float*)d_in[6];
    const float* Wg2 = (const float*)d_in[7];
    const float* bg2 = (const float*)d_in[8];
    const float* Wg3 = (const float*)d_in[9];
    const float* bg3 = (const float*)d_in[10];
    const float* Wd2 = (const float*)d_in[11];
    const float* bd2 = (const float*)d_in[12];
    float* out = (float*)d_out;

    int N  = in_sizes[0] / 4;       // N_FEAT = 4
    int E  = in_sizes[1] / 2;       // edge_index is [2, E]
    int NG = out_size / 128;        // 512 graphs
    const int* srcIdx = ei;
    const int* dstIdx = ei + E;
    int nbkt = (N + BSZ - 1) >> BSHIFT;     // 391 for N=100000

    char* p = (char*)d_ws;
    auto alloc = [&](size_t bytes) -> char* {
        char* r = p;
        p += (bytes + 255) & ~(size_t)255;
        return r;
    };
    int*    bktFill = (int*)alloc((size_t)nbkt * CPAD * 4);
    int*    staged  = (int*)alloc(((size_t)nbkt << CAPSH) * 4);   // 12.8 MB
    int*    col     = (int*)alloc(((size_t)nbkt << CAPSH) * 4);   // 12.8 MB
    int2*   rpe     = (int2*)alloc((size_t)N * 8);
    float*  dis     = (float*)alloc((size_t)N * 4);
    int*    gs      = (int*)alloc(((size_t)NG + 1) * 4);
    float*  sums    = (float*)alloc((size_t)NG * 128 * 4);
    __half* WT2     = (__half*)alloc(16384 * 2);
    __half* WT3     = (__half*)alloc(16384 * 2);
    __half* gA      = (__half*)alloc((size_t)N * 128 * 2);
    __half* gB      = (__half*)alloc((size_t)N * 128 * 2);
    __half* xT      = (__half*)alloc((size_t)N * 128 * 2);        // layer out
    (void)ws_size; (void)n_in;

    int BINB = (E + 4095) / 4096;               // 391
    int L1B  = (N + 63) / 64;                   // 1563
    int NB1  = (N + 511) / 512;                 // 196
    int ZB   = (NG * 128 + 511) / 512;          // 128
    int prepB = BINB + L1B + 32 + NB1 + ZB;
    int nb16 = (N + 15) / 16;                   // 6250
    int gridH = ((nb16 + 3) / 4) * 8;           // 12504 (nb,half) pairs

    hipMemsetAsync(bktFill, 0, (size_t)nbkt * CPAD * 4, stream);  // 50 KB

    k_prep<<<prepB, 512, 0, stream>>>(x, Wd1, bd1, Wg1, gA, Wg2, Wg3, WT2, WT3,
                                      batch, gs, srcIdx, dstIdx, bktFill,
                                      staged, sums, N, NG, E, nbkt,
                                      BINB, L1B, NB1);
    k_fineB<<<nbkt, 1024, 0, stream>>>(staged, bktFill, rpe, dis, col, N);

    // layer1: gA unscaled -> per-edge dis; then mm folds dis into gB rows
    k_aggH<true><<<gridH, 256, 0, stream>>>(gA, rpe, col, dis, bg1, xT, N, nb16);
    k_mm<<<nb16, 256, 0, stream>>>(xT, WT2, dis, gB, N);
    // layer2: gB pre-scaled -> plain adds
    k_aggH<false><<<gridH, 256, 0, stream>>>(gB, rpe, col, dis, bg2, xT, N, nb16);
    k_mm<<<nb16, 256, 0, stream>>>(xT, WT3, dis, gA, N);
    // layer3 + pool
    k_aggsumH<<<gridH, 256, 0, stream>>>(gA, rpe, col, dis, bg3, batch, sums,
                                         N, nb16);

    k_head<<<NG, 128, 0, stream>>>(sums, gs, Wd2, bd2, out);
}

// Round 2
// 307.479 us; speedup vs baseline: 1.3531x; 1.3531x over previous
//
#include <hip/hip_runtime.h>
#include <hip/hip_fp16.h>

// ---------------------------------------------------------------------------
// FormulaNet GCN forward: 3x GCNConv(128) + mean-pool(512 graphs) + dense.
// R2 fp16 tensors | R4 bucket CSR | R7 prep mega-kernel | R10 paired gathers
// R12 aggsum LDS slots | R16 fineB occupancy+cache [BEST 356.8]
// R17 LESSON: agg is random-ACCESS-rate bound, not byte bound (column split
//      halved footprint, FETCH 201->171 MB, duration unchanged). Reverted.
// R18: layer-1 linearity swap. A(H@W) = (A@H)@W and H0 is 4-dim: aggregate
//      4-dim h0 (8 B/row, 0.8 MB = L2-resident) instead of 128-dim g
//      (256 B/row, 25.6 MB). Deletes one 80us full agg + 25.6 MB prep write;
//      adds k_agg4 (~10us) + k_mmL1 (~13us MFMA). Layers 2/3: R16 fused
//      kernels with R17's dis-prescale (mm scales rows by dis[node]) so no
//      per-edge dis gathers remain anywhere.
// ---------------------------------------------------------------------------

#define BSHIFT 8
#define BSZ    256          // nodes per bucket
#define MAXBKT 512          // LDS sizing bound (N <= 131072)
#define CPAD   32           // 1 counter / 128 B line for global cursors
#define CAPSH  13           // 8192 staged/col slots per bucket

typedef _Float16 half8 __attribute__((ext_vector_type(8)));
typedef float f32x4 __attribute__((ext_vector_type(4)));

#define RFL __builtin_amdgcn_readfirstlane

// ---- prep: bin | layer1(4-dim h0) | cvtW | bounds | zero(sums) ----
__global__ __launch_bounds__(512) void k_prep(
        const float* __restrict__ x, const float* __restrict__ Wd1,
        const float* __restrict__ bd1, __half* __restrict__ h0,
        const float* __restrict__ W2, const float* __restrict__ W3,
        __half* __restrict__ WT2, __half* __restrict__ WT3,
        const int* __restrict__ batch, int* __restrict__ gs,
        const int* __restrict__ src, const int* __restrict__ dst,
        int* __restrict__ bktFill, int* __restrict__ staged,
        float* __restrict__ sums,
        int N, int NG, int E, int nbkt, int BINB, int L1B, int NB1) {
    __shared__ int hh[MAXBKT], base[MAXBKT], cur[MAXBKT];
    int bid = blockIdx.x;
    int t = threadIdx.x;
    if (bid < BINB) {
        // ---- bin: 4096 edges/block; LDS hist -> reservation -> scatter
        for (int i = t; i < nbkt; i += 512) { hh[i] = 0; cur[i] = 0; }
        __syncthreads();
        int e0 = bid * 4096 + t;
#pragma unroll
        for (int k = 0; k < 8; k++) {
            int e = e0 + k * 512;
            if (e < E) atomicAdd(&hh[dst[e] >> BSHIFT], 1);
        }
        __syncthreads();
        for (int i = t; i < nbkt; i += 512)
            base[i] = hh[i] ? atomicAdd(&bktFill[(size_t)i * CPAD], hh[i]) : 0;
        __syncthreads();
#pragma unroll
        for (int k = 0; k < 8; k++) {
            int e = e0 + k * 512;
            if (e < E) {
                int d = dst[e], s = src[e];
                int b = d >> BSHIFT;
                int off = atomicAdd(&cur[b], 1);
                staged[((size_t)b << CAPSH) + base[b] + off] =
                    ((d & (BSZ - 1)) << 17) | s;
            }
        }
    } else if (bid < BINB + L1B) {
        // ---- layer1 front: h0 = relu(x@Wd1+bd1), 4-dim fp16 (8 B/node)
        int node = (bid - BINB) * 512 + t;
        if (node < N) {
            float4 xv = ((const float4*)x)[node];
            float h[4];
#pragma unroll
            for (int k = 0; k < 4; k++) {
                float v = xv.x * Wd1[k] + xv.y * Wd1[4 + k]
                        + xv.z * Wd1[8 + k] + xv.w * Wd1[12 + k] + bd1[k];
                h[k] = fmaxf(v, 0.f);
            }
            __half2 o01 = __floats2half2_rn(h[0], h[1]);
            __half2 o23 = __floats2half2_rn(h[2], h[3]);
            uint2 pk;
            pk.x = *(unsigned*)&o01; pk.y = *(unsigned*)&o23;
            *(uint2*)(h0 + (size_t)node * 4) = pk;
        }
    } else if (bid < BINB + L1B + 32) {
        // ---- cvtW: W fp32 [k][n] -> WT fp16 [n][k], both layers
        int t2 = (bid - BINB - L1B) * 512 + t;      // 0..16383
        int k = t2 >> 7, nn = t2 & 127;
        WT2[nn * 128 + k] = __float2half_rn(W2[t2]);
        WT3[nn * 128 + k] = __float2half_rn(W3[t2]);
    } else if (bid < BINB + L1B + 32 + NB1) {
        // ---- bounds: batch sorted -> per-graph node ranges
        int i = (bid - BINB - L1B - 32) * 512 + t;
        if (i >= N) return;
        int b = batch[i];
        int prev = (i == 0) ? -1 : batch[i - 1];
        for (int g2 = prev + 1; g2 <= b; ++g2) gs[g2] = i;
        if (i == N - 1)
            for (int g2 = b + 1; g2 <= NG; ++g2) gs[g2] = N;
    } else {
        // ---- zero sums
        int idx = (bid - BINB - L1B - 32 - NB1) * 512 + t;
        if (idx < NG * 128) sums[idx] = 0.f;
    }
}

// ---- per-bucket: load+hist in LDS -> scan -> scatter; + dis & h0s=dis*h0 ----
__global__ __launch_bounds__(1024) void k_fineB(
        const int* __restrict__ staged, const int* __restrict__ bktFill,
        int2* __restrict__ rpe, float* __restrict__ dis,
        int* __restrict__ col, const __half* __restrict__ h0,
        __half* __restrict__ h0s, int N) {
    __shared__ int sEnt[1 << CAPSH];        // 32 KB bucket cache
    __shared__ int cnt[BSZ];
    __shared__ int incl[BSZ];
    int b = blockIdx.x;
    int lo = b << CAPSH;
    int cntE = bktFill[(size_t)b * CPAD];
    int n0 = b << BSHIFT;
    int tid = threadIdx.x;
    if (tid < BSZ) cnt[tid] = 0;
    __syncthreads();
    // fused: stage entries in LDS + histogram
    for (int e = tid; e < cntE; e += 1024) {
        int v = staged[lo + e];
        sEnt[e] = v;
        atomicAdd(&cnt[v >> 17], 1);
    }
    __syncthreads();
    int v = 0;
    if (tid < BSZ) { v = cnt[tid]; incl[tid] = v; }
    for (int off = 1; off < BSZ; off <<= 1) {
        __syncthreads();
        int t = (tid < BSZ && tid >= off) ? incl[tid - off] : 0;
        __syncthreads();
        if (tid < BSZ) incl[tid] += t;
    }
    __syncthreads();
    int myofs = 0;
    if (tid < BSZ) {
        myofs = incl[tid] - v;                 // exclusive
        int node = n0 + tid;
        if (node < N) {
            rpe[node] = make_int2(lo + myofs, lo + myofs + v);
            float dloc = rsqrtf((float)(v + 1));   // +1: self-loop
            dis[node] = dloc;
            uint2 hv = *(const uint2*)(h0 + (size_t)node * 4);
            float2 a01 = __half22float2(*(__half2*)&hv.x);
            float2 a23 = __half22float2(*(__half2*)&hv.y);
            __half2 o01 = __floats2half2_rn(a01.x * dloc, a01.y * dloc);
            __half2 o23 = __floats2half2_rn(a23.x * dloc, a23.y * dloc);
            uint2 pk;
            pk.x = *(unsigned*)&o01; pk.y = *(unsigned*)&o23;
            *(uint2*)(h0s + (size_t)node * 4) = pk;
        }
    }
    __syncthreads();
    // reuse incl[] as base table, cnt[] as cursors
    if (tid < BSZ) { incl[tid] = myofs; cnt[tid] = 0; }
    __syncthreads();
    for (int e = tid; e < cntE; e += 1024) {
        int ent = sEnt[e];
        int dl = ent >> 17;
        int pos = lo + incl[dl] + atomicAdd(&cnt[dl], 1);
        col[pos] = ent & 0x1FFFF;
    }
}

// ---- 4-dim aggregation: agg4[n] = dis[n]*(h0s[n] + sum h0s[col]) fp32 ----
__device__ __forceinline__ void addv4(float a[4], uint2 v) {
    float2 x01 = __half22float2(*(__half2*)&v.x);
    float2 x23 = __half22float2(*(__half2*)&v.y);
    a[0] += x01.x; a[1] += x01.y; a[2] += x23.x; a[3] += x23.y;
}

__global__ __launch_bounds__(256) void k_agg4(
        const __half* __restrict__ h0s, const int2* __restrict__ rpe,
        const float* __restrict__ dis, const int* __restrict__ col,
        float4* __restrict__ agg4, int N) {
    int n = blockIdx.x * 256 + threadIdx.x;
    if (n >= N) return;
    int2 re = rpe[n];
    float di = dis[n];
    float a[4];
    {   // self (h0s already dis-scaled)
        uint2 sv = *(const uint2*)(h0s + (size_t)n * 4);
        float2 s01 = __half22float2(*(__half2*)&sv.x);
        float2 s23 = __half22float2(*(__half2*)&sv.y);
        a[0] = s01.x; a[1] = s01.y; a[2] = s23.x; a[3] = s23.y;
    }
    int e = re.x, r1 = re.y;
    for (; e + 3 < r1; e += 4) {
        int c0 = col[e], c1 = col[e + 1], c2 = col[e + 2], c3 = col[e + 3];
        uint2 v0 = *(const uint2*)(h0s + (size_t)c0 * 4);
        uint2 v1 = *(const uint2*)(h0s + (size_t)c1 * 4);
        uint2 v2 = *(const uint2*)(h0s + (size_t)c2 * 4);
        uint2 v3 = *(const uint2*)(h0s + (size_t)c3 * 4);
        addv4(a, v0); addv4(a, v1); addv4(a, v2); addv4(a, v3);
    }
    for (; e < r1; ++e) {
        uint2 v0 = *(const uint2*)(h0s + (size_t)col[e] * 4);
        addv4(a, v0);
    }
    agg4[n] = make_float4(di * a[0], di * a[1], di * a[2], di * a[3]);
}

// ---- layer1 back-end: X1 = relu(agg4@Wg1+b1); gout = dis*(X1@W2) (MFMA) ----
__global__ __launch_bounds__(256) void k_mmL1(
        const float4* __restrict__ agg4, const float* __restrict__ Wg1,
        const float* __restrict__ b1, const __half* __restrict__ WT2,
        const float* __restrict__ dis, __half* __restrict__ gout, int n) {
    __shared__ float sW[512];
    __shared__ float sB[128];
    __shared__ _Float16 sH[16 * 136];
    __shared__ _Float16 sO[16 * 136];
    __shared__ float sDis[16];
    int t = threadIdx.x;
    sW[t] = Wg1[t];
    sW[t + 256] = Wg1[t + 256];
    if (t < 128) sB[t] = b1[t];
    int node0 = blockIdx.x * 16;
    int row = t >> 4, seg = t & 15;
    if (t < 16) sDis[t] = (node0 + t < n) ? dis[node0 + t] : 0.f;
    int nodeR = node0 + row;
    float4 av = (nodeR < n) ? agg4[nodeR] : make_float4(0.f, 0.f, 0.f, 0.f);
    __syncthreads();
    half8 hv;
#pragma unroll
    for (int u = 0; u < 8; u++) {
        int j = seg * 8 + u;
        float vv = sB[j] + av.x * sW[j] + av.y * sW[128 + j]
                 + av.z * sW[256 + j] + av.w * sW[384 + j];
        hv[u] = (_Float16)fmaxf(vv, 0.f);
    }
    *(half8*)&sH[row * 136 + seg * 8] = hv;
    __syncthreads();
    // mm: wave covers cols [wave*32, wave*32+32) for all 16 rows
    int wave = t >> 6, lane = t & 63;
    int q = lane >> 4, c = lane & 15;
    int n0 = wave * 32;
    f32x4 acc0 = {0.f, 0.f, 0.f, 0.f}, acc1 = {0.f, 0.f, 0.f, 0.f};
#pragma unroll
    for (int ks = 0; ks < 4; ks++) {
        int k0 = ks * 32;
        half8 a  = *(half8*)&sH[c * 136 + k0 + q * 8];
        half8 b0 = *(const half8*)(WT2 + (size_t)(n0 + c) * 128 + k0 + q * 8);
        half8 b1v = *(const half8*)(WT2 + (size_t)(n0 + 16 + c) * 128 + k0 + q * 8);
        acc0 = __builtin_amdgcn_mfma_f32_16x16x32_f16(a, b0, acc0, 0, 0, 0);
        acc1 = __builtin_amdgcn_mfma_f32_16x16x32_f16(a, b1v, acc1, 0, 0, 0);
    }
#pragma unroll
    for (int r = 0; r < 4; r++) {
        int rr = q * 4 + r;
        sO[rr * 136 + n0 + c]      = (_Float16)(acc0[r] * sDis[rr]);
        sO[rr * 136 + n0 + 16 + c] = (_Float16)(acc1[r] * sDis[rr]);
    }
    __syncthreads();
    if (nodeR < n)
        *(uint4*)(gout + (size_t)nodeR * 128 + seg * 8) =
            *(uint4*)&sO[row * 136 + seg * 8];
}

// paired-edge aggregation, pre-scaled input (no per-edge dis): half-wave hf
// covers edge e+hf's FULL row (8 B/lane = 4 halfs, lanes sl=0..31 -> feats
// 4sl..4sl+3). After the loop, shfl_xor(32) combines halves.
__device__ __forceinline__ void acc4r(float acc[4], uint2 v) {
    float2 a01 = __half22float2(*(__half2*)&v.x);
    float2 a23 = __half22float2(*(__half2*)&v.y);
    acc[0] += a01.x; acc[1] += a01.y; acc[2] += a23.x; acc[3] += a23.y;
}

__device__ __forceinline__ void agg_node4(
        const __half* __restrict__ g, const int* __restrict__ col,
        int r0, int r1, int node, int hf, int sl, float acc[4]) {
    uint2 mr = *(const uint2*)(g + (size_t)node * 128 + sl * 4);
    float2 m01 = __half22float2(*(__half2*)&mr.x);
    float2 m23 = __half22float2(*(__half2*)&mr.y);
    float sw = hf ? 0.f : 1.f;              // self-loop on half 0 only
    acc[0] = sw * m01.x; acc[1] = sw * m01.y;
    acc[2] = sw * m23.x; acc[3] = sw * m23.y;
    int e = r0;
    for (; e + 7 < r1; e += 8) {            // 4 pairs in flight
        int sa0 = RFL(col[e]),     sb0 = RFL(col[e + 1]);
        int sa1 = RFL(col[e + 2]), sb1 = RFL(col[e + 3]);
        int sa2 = RFL(col[e + 4]), sb2 = RFL(col[e + 5]);
        int sa3 = RFL(col[e + 6]), sb3 = RFL(col[e + 7]);
        int s0 = hf ? sb0 : sa0;
        int s1 = hf ? sb1 : sa1;
        int s2 = hf ? sb2 : sa2;
        int s3 = hf ? sb3 : sa3;
        uint2 r0v = *(const uint2*)(g + (size_t)s0 * 128 + sl * 4);
        uint2 r1v = *(const uint2*)(g + (size_t)s1 * 128 + sl * 4);
        uint2 r2v = *(const uint2*)(g + (size_t)s2 * 128 + sl * 4);
        uint2 r3v = *(const uint2*)(g + (size_t)s3 * 128 + sl * 4);
        acc4r(acc, r0v); acc4r(acc, r1v); acc4r(acc, r2v); acc4r(acc, r3v);
    }
    for (; e + 1 < r1; e += 2) {
        int sa = RFL(col[e]), sb = RFL(col[e + 1]);
        int s = hf ? sb : sa;
        uint2 rv = *(const uint2*)(g + (size_t)s * 128 + sl * 4);
        acc4r(acc, rv);
    }
    if (e < r1) {                           // odd tail: half 1 contributes 0
        int sa = RFL(col[e]);
        uint2 rv = *(const uint2*)(g + (size_t)sa * 128 + sl * 4);
        if (!hf) acc4r(acc, rv);
    }
#pragma unroll
    for (int k = 0; k < 4; k++) acc[k] += __shfl_xor(acc[k], 32);
}

// fused GCN layer: block = 16 nodes (4 waves x 4 serial nodes).
// agg (+bias,relu) -> LDS rows -> mfma 16x16x32 -> gout = dis*(X@WT).
__global__ __launch_bounds__(256) void k_aggmm(
        const __half* __restrict__ gin, const int2* __restrict__ rpe,
        const int* __restrict__ col, const float* __restrict__ dis,
        const float* __restrict__ bias, const __half* __restrict__ WT,
        __half* __restrict__ gout, int n) {
    __shared__ _Float16 sH[16 * 136];
    __shared__ _Float16 sO[16 * 136];
    __shared__ float sDis[16];
    int t = threadIdx.x;
    int wave = t >> 6, lane = t & 63;
    int hf = lane >> 5, sl = lane & 31;
    int node0 = blockIdx.x * 16;
    if (t < 16) sDis[t] = (node0 + t < n) ? dis[node0 + t] : 0.f;
    float4 bb = ((const float4*)bias)[sl];
#pragma unroll
    for (int i = 0; i < 4; i++) {
        int node = RFL(node0 + wave * 4 + i);
        if (node < n) {
            int2 re = rpe[node];
            int r0 = RFL(re.x);
            int r1 = RFL(re.y);
            float di = dis[node];
            float acc[4];
            agg_node4(gin, col, r0, r1, node, hf, sl, acc);
            if (hf == 0) {
                int lr = wave * 4 + i;
                __half2 o01 = __floats2half2_rn(
                    fmaxf(fmaf(di, acc[0], bb.x), 0.f),
                    fmaxf(fmaf(di, acc[1], bb.y), 0.f));
                __half2 o23 = __floats2half2_rn(
                    fmaxf(fmaf(di, acc[2], bb.z), 0.f),
                    fmaxf(fmaf(di, acc[3], bb.w), 0.f));
                uint2 pk;
                pk.x = *(unsigned*)&o01; pk.y = *(unsigned*)&o23;
                *(uint2*)&sH[lr * 136 + sl * 4] = pk;
            }
        }
    }
    __syncthreads();
    // mm: wave covers cols [wave*32, wave*32+32) for all 16 rows
    int q = lane >> 4, c = lane & 15;
    int n0 = wave * 32;
    f32x4 acc0 = {0.f, 0.f, 0.f, 0.f}, acc1 = {0.f, 0.f, 0.f, 0.f};
#pragma unroll
    for (int ks = 0; ks < 4; ks++) {
        int k0 = ks * 32;
        half8 a  = *(half8*)&sH[c * 136 + k0 + q * 8];
        half8 b0 = *(const half8*)(WT + (size_t)(n0 + c) * 128 + k0 + q * 8);
        half8 b1 = *(const half8*)(WT + (size_t)(n0 + 16 + c) * 128 + k0 + q * 8);
        acc0 = __builtin_amdgcn_mfma_f32_16x16x32_f16(a, b0, acc0, 0, 0, 0);
        acc1 = __builtin_amdgcn_mfma_f32_16x16x32_f16(a, b1, acc1, 0, 0, 0);
    }
#pragma unroll
    for (int r = 0; r < 4; r++) {
        int rr = q * 4 + r;
        sO[rr * 136 + n0 + c]      = (_Float16)(acc0[r] * sDis[rr]);
        sO[rr * 136 + n0 + 16 + c] = (_Float16)(acc1[r] * sDis[rr]);
    }
    __syncthreads();
    int lr2 = t >> 4, seg = t & 15;
    int rowN = node0 + lr2;
    if (rowN < n)
        *(uint4*)(gout + (size_t)rowN * 128 + seg * 8) =
            *(uint4*)&sO[lr2 * 136 + seg * 8];
}

// fused layer-3 agg + mean-pool (pre-scaled input). Single-graph blocks
// (~92%): per-wave register partials -> private LDS slots -> one barrier ->
// 128 global atomics per block. Boundary blocks: per-wave flush.
__global__ __launch_bounds__(256) void k_aggsum(
        const __half* __restrict__ gin, const int2* __restrict__ rpe,
        const int* __restrict__ col, const float* __restrict__ dis,
        const float* __restrict__ bias, const int* __restrict__ batch,
        float* __restrict__ sums, int n) {
    __shared__ float ls[4][128];
    int t = threadIdx.x;
    int wave = t >> 6, lane = t & 63;
    int hf = lane >> 5, sl = lane & 31;
    int nodeBase = blockIdx.x * 16;
    if (nodeBase >= n) return;
    int lastNode = min(nodeBase + 15, n - 1);
    int b0 = RFL(batch[nodeBase]);
    bool uni = (RFL(batch[lastNode]) == b0);
    float4 bb = ((const float4*)bias)[sl];
    float sx[4] = {0.f, 0.f, 0.f, 0.f};
    int curb = b0;
#pragma unroll
    for (int i = 0; i < 4; i++) {
        int node = RFL(nodeBase + wave * 4 + i);
        if (node < n) {
            int2 re = rpe[node];
            int r0 = RFL(re.x);
            int r1 = RFL(re.y);
            float di = dis[node];
            float acc[4];
            agg_node4(gin, col, r0, r1, node, hf, sl, acc);
            float o0 = fmaxf(fmaf(di, acc[0], bb.x), 0.f);
            float o1 = fmaxf(fmaf(di, acc[1], bb.y), 0.f);
            float o2 = fmaxf(fmaf(di, acc[2], bb.z), 0.f);
            float o3 = fmaxf(fmaf(di, acc[3], bb.w), 0.f);
            if (!uni) {
                int b = RFL(batch[node]);
                if (b != curb) {
                    if (hf == 0) {
                        atomicAdd(&sums[(size_t)curb * 128 + sl * 4 + 0], sx[0]);
                        atomicAdd(&sums[(size_t)curb * 128 + sl * 4 + 1], sx[1]);
                        atomicAdd(&sums[(size_t)curb * 128 + sl * 4 + 2], sx[2]);
                        atomicAdd(&sums[(size_t)curb * 128 + sl * 4 + 3], sx[3]);
                    }
                    sx[0] = sx[1] = sx[2] = sx[3] = 0.f;
                    curb = b;
                }
            }
            sx[0] += o0; sx[1] += o1; sx[2] += o2; sx[3] += o3;
        }
    }
    if (uni) {
        // slot-exclusive LDS write (hf==0 lanes cover all 128 feats)
        if (hf == 0) {
            ls[wave][sl * 4 + 0] = sx[0];
            ls[wave][sl * 4 + 1] = sx[1];
            ls[wave][sl * 4 + 2] = sx[2];
            ls[wave][sl * 4 + 3] = sx[3];
        }
        __syncthreads();
        if (t < 128) {
            float v = ls[0][t] + ls[1][t] + ls[2][t] + ls[3][t];
            atomicAdd(&sums[(size_t)b0 * 128 + t], v);
        }
    } else {
        if (hf == 0) {
            atomicAdd(&sums[(size_t)curb * 128 + sl * 4 + 0], sx[0]);
            atomicAdd(&sums[(size_t)curb * 128 + sl * 4 + 1], sx[1]);
            atomicAdd(&sums[(size_t)curb * 128 + sl * 4 + 2], sx[2]);
            atomicAdd(&sums[(size_t)curb * 128 + sl * 4 + 3], sx[3]);
        }
    }
}

// head: pooled = sums/cnt; out = pooled @ Wd2 + bd2. One block per graph.
__global__ __launch_bounds__(128) void k_head(
        const float* __restrict__ sums, const int* __restrict__ gs,
        const float* __restrict__ Wd2, const float* __restrict__ bd2,
        float* __restrict__ out) {
    int gidx = blockIdx.x;
    int j = threadIdx.x;
    int c = gs[gidx + 1] - gs[gidx];
    float inv = 1.0f / (float)(c > 1 ? c : 1);
    __shared__ float sp[128];
    sp[j] = sums[(size_t)gidx * 128 + j] * inv;
    __syncthreads();
    float o = bd2[j];
#pragma unroll 8
    for (int k = 0; k < 128; k++) o = fmaf(sp[k], Wd2[k * 128 + j], o);
    out[gidx * 128 + j] = o;
}

extern "C" void kernel_launch(void* const* d_in, const int* in_sizes, int n_in,
                              void* d_out, int out_size, void* d_ws, size_t ws_size,
                              hipStream_t stream) {
    const float* x   = (const float*)d_in[0];
    const int*  ei   = (const int*)d_in[1];
    const int* batch = (const int*)d_in[2];
    const float* Wd1 = (const float*)d_in[3];
    const float* bd1 = (const float*)d_in[4];
    const float* Wg1 = (const float*)d_in[5];
    const float* bg1 = (const float*)d_in[6];
    const float* Wg2 = (const float*)d_in[7];
    const float* bg2 = (const float*)d_in[8];
    const float* Wg3 = (const float*)d_in[9];
    const float* bg3 = (const float*)d_in[10];
    const float* Wd2 = (const float*)d_in[11];
    const float* bd2 = (const float*)d_in[12];
    float* out = (float*)d_out;

    int N  = in_sizes[0] / 4;       // N_FEAT = 4
    int E  = in_sizes[1] / 2;       // edge_index is [2, E]
    int NG = out_size / 128;        // 512 graphs
    const int* srcIdx = ei;
    const int* dstIdx = ei + E;
    int nbkt = (N + BSZ - 1) >> BSHIFT;     // 391 for N=100000

    char* p = (char*)d_ws;
    auto alloc = [&](size_t bytes) -> char* {
        char* r = p;
        p += (bytes + 255) & ~(size_t)255;
        return r;
    };
    int*    bktFill = (int*)alloc((size_t)nbkt * CPAD * 4);
    int*    staged  = (int*)alloc(((size_t)nbkt << CAPSH) * 4);   // 12.8 MB
    int*    col     = (int*)alloc(((size_t)nbkt << CAPSH) * 4);   // 12.8 MB
    int2*   rpe     = (int2*)alloc((size_t)N * 8);
    float*  dis     = (float*)alloc((size_t)N * 4);
    int*    gs      = (int*)alloc(((size_t)NG + 1) * 4);
    float*  sums    = (float*)alloc((size_t)NG * 128 * 4);
    __half* WT2     = (__half*)alloc(16384 * 2);
    __half* WT3     = (__half*)alloc(16384 * 2);
    __half* gA      = (__half*)alloc((size_t)N * 128 * 2);
    __half* gB      = (__half*)alloc((size_t)N * 128 * 2);
    __half* h0      = (__half*)alloc((size_t)N * 4 * 2);          // 0.8 MB
    __half* h0s     = (__half*)alloc((size_t)N * 4 * 2);          // 0.8 MB
    float4* agg4    = (float4*)alloc((size_t)N * 16);             // 1.6 MB
    (void)ws_size; (void)n_in;

    int BINB = (E + 4095) / 4096;               // 391
    int L1B  = (N + 511) / 512;                 // 196
    int NB1  = (N + 511) / 512;                 // 196
    int ZB   = (NG * 128 + 511) / 512;          // 128
    int prepB = BINB + L1B + 32 + NB1 + ZB;
    int nb16 = (N + 15) / 16;                   // 6250

    hipMemsetAsync(bktFill, 0, (size_t)nbkt * CPAD * 4, stream);  // 50 KB

    k_prep<<<prepB, 512, 0, stream>>>(x, Wd1, bd1, h0, Wg2, Wg3, WT2, WT3,
                                      batch, gs, srcIdx, dstIdx, bktFill,
                                      staged, sums, N, NG, E, nbkt,
                                      BINB, L1B, NB1);
    k_fineB<<<nbkt, 1024, 0, stream>>>(staged, bktFill, rpe, dis, col,
                                       h0, h0s, N);

    // layer1: 4-dim agg (L2-resident) then X1 = relu(agg4@Wg1+b1),
    // gB = dis * (X1@W2) via MFMA
    k_agg4<<<(N + 255) / 256, 256, 0, stream>>>(h0s, rpe, dis, col, agg4, N);
    k_mmL1<<<nb16, 256, 0, stream>>>(agg4, Wg1, bg1, WT2, dis, gB, N);
    // layer2: full-row fused agg+mm (pre-scaled input, no per-edge dis)
    k_aggmm<<<nb16, 256, 0, stream>>>(gB, rpe, col, dis, bg2, WT3, gA, N);
    // layer3 + pool
    k_aggsum<<<nb16, 256, 0, stream>>>(gA, rpe, col, dis, bg3, batch, sums, N);

    k_head<<<NG, 128, 0, stream>>>(sums, gs, Wd2, bd2, out);
}